// Round 3
// baseline (3635.583 us; speedup 1.0000x reference)
//
#include <hip/hip_runtime.h>
#include <stdint.h>

// BinaryAttention on MI355X (gfx950).  B=64, N=197, C=768, H=12, d=64.
//
// ROUND 14 — resubmit of R13 (bench infra failed twice; no kernel signal).
// R13 theory: R12 passed at 3362 us with qkv_g = 2.26 ms VALU-bound
// (VALUBusy 66%, MfmaUtil 0, HBM 8%, conflicts 0) vs 0.57 ms f64-FMA floor.
// Inner loop re-converted x f32->f64 per FMA (288 cvt + 288 ds_read_b32 per
// 256 FMAs). This version (accumulation order per output BIT-IDENTICAL):
//   * x (and proj's int acc) staged in LDS as f64, converted ONCE at stage;
//     inner loop reads double2 (broadcast ds_read_b128, conflict-free).
//   * RQ 8 -> 16 rows/block: 2x FMAs per staged weight tile.
//   * attn PV parallelized across all 4 waves (int partials, associative ->
//     exactly deterministic).

#define NT 197
#define HH 12
#define CD 768
#define NB 64
#define MROWS (NB * NT)   // 12608
#define NBH (NB * HH)     // 768
#define RQ 16             // rows per block in the two GEMM kernels
#define YB (MROWS / RQ)   // 788

// ---- flag-selected flat indexers (flag: 0 = C-order, 1 = F-order) ----
__device__ __forceinline__ size_t idxX(int f, int b, int n, int c) {
  return f ? ((size_t)b + 64u * (size_t)n + 12608u * (size_t)c)
           : ((size_t)(b * NT + n) * CD + c);
}
__device__ __forceinline__ size_t idxRT(int f, int i, int h) {  // rel_table [732,12]
  return f ? ((size_t)i + 732u * (size_t)h) : ((size_t)i * HH + h);
}
__device__ __forceinline__ size_t idxRI(int f, int n, int m) {  // rel_index [197,197]
  return f ? ((size_t)n + 197u * (size_t)m) : ((size_t)n * NT + m);
}

// ---- orientation probe (deterministic rel_index: C: ri[1]=729, ri[197]=730) --
__global__ __launch_bounds__(64) void probe_orient(const int* __restrict__ ri,
                                                   int* __restrict__ flag) {
  if (threadIdx.x == 0) {
    const int a = ri[1], b = ri[197];
    flag[0] = (a == 730 && b == 729) ? 1 : 0;
  }
}

// ---------- 1) qkv GEMM, f64 accum, LDS-tiled, 16 rows/block ----------
// grid (9, 788), block 256. c = blockIdx.x*256 + t; rows row0..row0+15.
__global__ __launch_bounds__(256) void qkv_g(
    const float* __restrict__ x, const float* __restrict__ w,
    uint64_t* __restrict__ qbits, uint64_t* __restrict__ kbits,
    int8_t* __restrict__ vq8, double* __restrict__ qpart,
    double* __restrict__ kpart, const int* __restrict__ flag) {
  __shared__ float wsm[256][33];     // +1 pad: conflict-free column reads
  __shared__ double xsm[RQ][32];     // staged f64 (broadcast reads)

  const int f = flag[0];
  const int t = threadIdx.x;
  const int cBase = blockIdx.x * 256;
  const int c = cBase + t;              // 0..2303
  const int row0 = blockIdx.y * RQ;

  double acc[RQ];
  #pragma unroll
  for (int i = 0; i < RQ; i++) acc[i] = 0.0;

  if (f == 0) {
    for (int k0 = 0; k0 < CD; k0 += 32) {
      // stage w tile [256 c][32 k] via coalesced float4 (8 lines/wave-instr)
      #pragma unroll
      for (int j = 0; j < 8; j++) {
        const int flat = t + 256 * j;          // 0..2047
        const int r = flat >> 3, kq = flat & 7;
        const float4 v4 = *reinterpret_cast<const float4*>(
            w + (size_t)(cBase + r) * CD + k0 + kq * 4);
        wsm[r][kq * 4 + 0] = v4.x; wsm[r][kq * 4 + 1] = v4.y;
        wsm[r][kq * 4 + 2] = v4.z; wsm[r][kq * 4 + 3] = v4.w;
      }
      // stage x [16 rows][32 k] -> f64 (convert ONCE here)
      #pragma unroll
      for (int j = 0; j < 2; j++) {
        const int flat = t + 256 * j;          // 0..511
        const int r = flat >> 5, kk = flat & 31;
        xsm[r][kk] = (double)x[(size_t)(row0 + r) * CD + k0 + kk];
      }
      __syncthreads();
      // ascending kk per acc[i]: bit-identical accumulation order to R12
      for (int kk = 0; kk < 32; kk += 2) {
        const double w0 = (double)wsm[t][kk];
        const double w1 = (double)wsm[t][kk + 1];
        #pragma unroll
        for (int i = 0; i < RQ; i++) {
          const double2 xv = *reinterpret_cast<const double2*>(&xsm[i][kk]);
          acc[i] += xv.x * w0;
          acc[i] += xv.y * w1;
        }
      }
      __syncthreads();
    }
  } else {
    // F-order: consecutive out-channels contiguous -> already coalesced
    for (int k = 0; k < CD; k++) {
      const double wv = (double)w[(size_t)c + 2304u * (size_t)k];
      #pragma unroll
      for (int i = 0; i < RQ; i++) {
        const int row = row0 + i, b = row / NT, n = row - b * NT;
        acc[i] += (double)x[(size_t)b + 64u * (size_t)n + 12608u * (size_t)k] * wv;
      }
    }
  }

  // fused quantize epilogue (identical per-row math to R12)
  const int kind = cBase / CD;              // uniform per block (768 % 256 == 0)
  const int h = (c - kind * CD) >> 6;       // uniform per wave
  const int lane = t & 63;                  // == dd
  #pragma unroll
  for (int i = 0; i < RQ; i++) {
    const int row = row0 + i, b = row / NT, n = row - b * NT;
    const int bh = b * HH + h;
    const double a = acc[i];
    if (kind == 2) {
      const double sV = 2.0 / 127.0;
      double vc = fmin(fmax(a, -2.0), 2.0);
      double vq = rint(vc / sV);
      vq = fmin(fmax(vq, -127.0), 127.0);
      vq8[(size_t)(bh * NT + n) * 64 + lane] = (int8_t)(int)vq;
    } else {
      const uint64_t msk = __ballot(a < 0.0);
      double s = fabs(a);
      #pragma unroll
      for (int off = 1; off < 64; off <<= 1) s += __shfl_xor(s, off);
      if (lane == 0) {
        if (kind == 0) { qbits[(size_t)bh * NT + n] = msk; qpart[(size_t)bh * NT + n] = s; }
        else           { kbits[(size_t)bh * NT + n] = msk; kpart[(size_t)bh * NT + n] = s; }
      }
    }
  }
}

// ---------- 1b) deterministic fixed-order reduction of row partials ----------
// grid (768), block 256. sqa[bh] = sum_n qpart[bh*197+n] in a FIXED tree order.
__global__ __launch_bounds__(256) void reduce_s(
    const double* __restrict__ qpart, const double* __restrict__ kpart,
    double* __restrict__ sqa, double* __restrict__ ska) {
  __shared__ double sh[256];
  const int bh = blockIdx.x, t = threadIdx.x;
  sh[t] = (t < NT) ? qpart[(size_t)bh * NT + t] : 0.0;
  __syncthreads();
  for (int s = 128; s > 0; s >>= 1) { if (t < s) sh[t] += sh[t + s]; __syncthreads(); }
  if (t == 0) sqa[bh] = sh[0];
  __syncthreads();
  sh[t] = (t < NT) ? kpart[(size_t)bh * NT + t] : 0.0;
  __syncthreads();
  for (int s = 128; s > 0; s >>= 1) { if (t < s) sh[t] += sh[t + s]; __syncthreads(); }
  if (t == 0) ska[bh] = sh[0];
}

// ---------- 2) attention in f64: one block per (b,h,n) ----------
// grid (197, 768), block 256. Deterministic tree max/sum; int32 PV, 4-wave.
__global__ __launch_bounds__(256) void attn_f64(
    const uint64_t* __restrict__ qbits, const uint64_t* __restrict__ kbits,
    const int8_t* __restrict__ vq8, const double* __restrict__ sqa,
    const double* __restrict__ ska, const float* __restrict__ rel_table,
    const int* __restrict__ rel_index, int* __restrict__ attn_acc,
    const int* __restrict__ flag) {
  __shared__ double ls[256];
  __shared__ double es[256];
  __shared__ int Pu[NT];
  __shared__ int part[4][64];

  const int f = flag[0];
  const int n = blockIdx.x;
  const int bh = blockIdx.y;
  const int b = bh / HH, h = bh - b * HH;
  const int t = threadIdx.x;

  const double s_q = sqa[bh] / (double)(NT * 64);
  const double s_k = ska[bh] / (double)(NT * 64);
  const double coef = s_q * s_k * 0.125;
  const uint64_t qb = qbits[(size_t)bh * NT + n];
  const uint64_t* kb = kbits + (size_t)bh * NT;

  double lt;
  if (t < NT) {
    const int dot = 64 - 2 * (int)__popcll(qb ^ kb[t]);
    lt = coef * (double)dot +
         (double)rel_table[idxRT(f, rel_index[idxRI(f, n, t)], h)];
  } else {
    lt = -1e300;
  }
  ls[t] = lt;
  __syncthreads();
  for (int s = 128; s > 0; s >>= 1) {      // exact max (order-independent)
    if (t < s) ls[t] = fmax(ls[t], ls[t + s]);
    __syncthreads();
  }
  const double mx = ls[0];
  const double et = (t < NT) ? exp(lt - mx) : 0.0;
  es[t] = et;
  __syncthreads();
  for (int s = 128; s > 0; s >>= 1) {      // fixed-order sum (deterministic)
    if (t < s) es[t] += es[t + s];
    __syncthreads();
  }
  const double sum = es[0];

  if (t < NT) {
    const double sP = 1.0 / 255.0;
    double P = rint((et / sum) / sP);
    P = fmin(fmax(P, 0.0), 255.0);
    Pu[t] = (int)P;
  }
  __syncthreads();

  // PV: all 4 waves, each takes ~50 of the 197 m-iterations. Int partials:
  // integer addition is associative -> exactly deterministic.
  {
    const int wv = t >> 6, dd = t & 63;
    const int m0 = wv * 50, m1 = (wv == 3) ? NT : m0 + 50;
    const int8_t* vb = vq8 + (size_t)bh * NT * 64 + dd;
    int acc = 0;
    for (int m = m0; m < m1; m++) acc += Pu[m] * (int)vb[(size_t)m * 64];
    part[wv][dd] = acc;
  }
  __syncthreads();
  if (t < 64) {
    const int acc = part[0][t] + part[1][t] + part[2][t] + part[3][t];
    attn_acc[(size_t)(b * NT + n) * CD + h * 64 + t] = acc;
  }
}

// ---------- 3) proj GEMM, f64 accum, LDS-tiled, 16 rows/block ----------
// grid (3, 788), block 256. out = (sum acc_int*w)*sP*sV + bias, fp32.
__global__ __launch_bounds__(256) void proj_g(
    const int* __restrict__ attn_acc, const float* __restrict__ w,
    const float* __restrict__ bias, float* __restrict__ out,
    const int* __restrict__ flag) {
  __shared__ float wsm[256][33];
  __shared__ double xsm[RQ][32];     // staged int->f64 (exact), broadcast reads

  const int f = flag[0];
  const int t = threadIdx.x;
  const int cBase = blockIdx.x * 256;
  const int c = cBase + t;                  // 0..767
  const int row0 = blockIdx.y * RQ;

  double acc[RQ];
  #pragma unroll
  for (int i = 0; i < RQ; i++) acc[i] = 0.0;

  if (f == 0) {
    for (int k0 = 0; k0 < CD; k0 += 32) {
      #pragma unroll
      for (int j = 0; j < 8; j++) {
        const int flat = t + 256 * j;
        const int r = flat >> 3, kq = flat & 7;
        const float4 v4 = *reinterpret_cast<const float4*>(
            w + (size_t)(cBase + r) * CD + k0 + kq * 4);
        wsm[r][kq * 4 + 0] = v4.x; wsm[r][kq * 4 + 1] = v4.y;
        wsm[r][kq * 4 + 2] = v4.z; wsm[r][kq * 4 + 3] = v4.w;
      }
      #pragma unroll
      for (int j = 0; j < 2; j++) {
        const int flat = t + 256 * j;          // 0..511
        const int r = flat >> 5, kk = flat & 31;
        xsm[r][kk] = (double)attn_acc[(size_t)(row0 + r) * CD + k0 + kk];
      }
      __syncthreads();
      for (int kk = 0; kk < 32; kk += 2) {
        const double w0 = (double)wsm[t][kk];
        const double w1 = (double)wsm[t][kk + 1];
        #pragma unroll
        for (int i = 0; i < RQ; i++) {
          const double2 xv = *reinterpret_cast<const double2*>(&xsm[i][kk]);
          acc[i] += xv.x * w0;
          acc[i] += xv.y * w1;
        }
      }
      __syncthreads();
    }
  } else {
    for (int k = 0; k < CD; k++) {
      const double wv = (double)w[(size_t)c + 768u * (size_t)k];
      #pragma unroll
      for (int i = 0; i < RQ; i++)
        acc[i] += (double)attn_acc[(size_t)(row0 + i) * CD + k] * wv;
    }
  }

  const double SCALE = (1.0 / 255.0) * (2.0 / 127.0);
  #pragma unroll
  for (int i = 0; i < RQ; i++) {
    const int row = row0 + i, b = row / NT, n = row - b * NT;
    out[idxX(f, b, n, c)] = (float)(acc[i] * SCALE + (double)bias[c]);
  }
}

// ---------------- host launch ----------------
extern "C" void kernel_launch(void* const* d_in, const int* in_sizes, int n_in,
                              void* d_out, int out_size, void* d_ws, size_t ws_size,
                              hipStream_t stream) {
  (void)out_size; (void)ws_size;

  // resolve inputs BY ELEMENT COUNT (all unique; fallback positional)
  const float* x = nullptr;
  const float* qkv_w = nullptr;
  const float* proj_w = nullptr;
  const float* proj_b = nullptr;
  const float* rel_table = nullptr;
  const int* rel_index = nullptr;
  for (int i = 0; i < n_in; i++) {
    switch (in_sizes[i]) {
      case 9682944: x         = (const float*)d_in[i]; break;
      case 1769472: qkv_w     = (const float*)d_in[i]; break;
      case 589824:  proj_w    = (const float*)d_in[i]; break;
      case 768:     proj_b    = (const float*)d_in[i]; break;
      case 8784:    rel_table = (const float*)d_in[i]; break;
      case 38809:   rel_index = (const int*)d_in[i];   break;
      default: break;
    }
  }
  if (!x)         x         = (const float*)d_in[0];
  if (!qkv_w)     qkv_w     = (const float*)d_in[1];
  if (!proj_w)    proj_w    = (const float*)d_in[2];
  if (!proj_b)    proj_b    = (const float*)d_in[3];
  if (!rel_table) rel_table = (const float*)d_in[4];
  if (!rel_index) rel_index = (const int*)d_in[5];
  float* out = (float*)d_out;

  uint8_t* ws = (uint8_t*)d_ws;
  // workspace (~53 MB), every byte written before read each call, no init:
  int*      flag     = (int*)(ws + 0);              //         64
  double*   sqa      = (double*)(ws + 64);          //      6,144
  double*   ska      = (double*)(ws + 6208);        //      6,144
  double*   qpart    = (double*)(ws + 12352);       //  1,210,368
  double*   kpart    = (double*)(ws + 1222720);     //  1,210,368
  uint64_t* qbits    = (uint64_t*)(ws + 2433088);   //  1,210,368
  uint64_t* kbits    = (uint64_t*)(ws + 3643456);   //  1,210,368
  int8_t*   vq8      = (int8_t*)(ws + 4853824);     //  9,682,944
  int*      attn_acc = (int*)(ws + 14536768);       // 38,731,776 -> 53,268,544

  probe_orient<<<1, 64, 0, stream>>>(rel_index, flag);
  qkv_g<<<dim3(9, YB), 256, 0, stream>>>(x, qkv_w, qbits, kbits, vq8,
                                         qpart, kpart, flag);
  reduce_s<<<NBH, 256, 0, stream>>>(qpart, kpart, sqa, ska);
  attn_f64<<<dim3(NT, NBH), 256, 0, stream>>>(qbits, kbits, vq8, sqa, ska,
                                              rel_table, rel_index, attn_acc, flag);
  proj_g<<<dim3(3, YB), 256, 0, stream>>>(attn_acc, proj_w, proj_b, out, flag);
}

// Round 4
// 2829.358 us; speedup vs baseline: 1.2850x; 1.2850x over previous
//
#include <hip/hip_runtime.h>
#include <stdint.h>

// BinaryAttention on MI355X (gfx950).  B=64, N=197, C=768, H=12, d=64.
//
// ROUND 15 — ILP FIX (R14 post-mortem: VALUBusy fell 66->33% at same dur =>
// latency-bound serial LDS chains; VGPR_Count=52 shows the compiler had no
// register headroom to preload x). Changes, all numerics bit-identical:
//   * qkv_g / proj_g: __launch_bounds__(256,4) (VGPR cap 128) + explicit
//     preload of 16 double2 x-values per kk-pair (16 independent
//     ds_read_b128 in flight before the 32-FMA burst). wsm padded to
//     [256][34] so the w pair is one aligned ds_read_b64 (2-way = free).
//   * attn_f64: one block per (b,h) looping n=0..196 (was one block per
//     (b,h,n)): stages q/k bitrows + V(int16) in LDS ONCE, removing 197x
//     redundant kb/vq8 loads (~2 GB L2 traffic) and 151K-block overhead.
//     Per-n trees / PV split / expressions copied verbatim (bit-identical).

#define NT 197
#define HH 12
#define CD 768
#define NB 64
#define MROWS (NB * NT)   // 12608
#define NBH (NB * HH)     // 768
#define RQ 16             // rows per block in the two GEMM kernels
#define YB (MROWS / RQ)   // 788

// ---- flag-selected flat indexers (flag: 0 = C-order, 1 = F-order) ----
__device__ __forceinline__ size_t idxX(int f, int b, int n, int c) {
  return f ? ((size_t)b + 64u * (size_t)n + 12608u * (size_t)c)
           : ((size_t)(b * NT + n) * CD + c);
}
__device__ __forceinline__ size_t idxRT(int f, int i, int h) {  // rel_table [732,12]
  return f ? ((size_t)i + 732u * (size_t)h) : ((size_t)i * HH + h);
}
__device__ __forceinline__ size_t idxRI(int f, int n, int m) {  // rel_index [197,197]
  return f ? ((size_t)n + 197u * (size_t)m) : ((size_t)n * NT + m);
}

// ---- orientation probe (deterministic rel_index: C: ri[1]=729, ri[197]=730) --
__global__ __launch_bounds__(64) void probe_orient(const int* __restrict__ ri,
                                                   int* __restrict__ flag) {
  if (threadIdx.x == 0) {
    const int a = ri[1], b = ri[197];
    flag[0] = (a == 730 && b == 729) ? 1 : 0;
  }
}

// ---------- 1) qkv GEMM, f64 accum, LDS-tiled, 16 rows/block ----------
// grid (9, 788), block 256. c = blockIdx.x*256 + t; rows row0..row0+15.
__global__ __launch_bounds__(256, 4) void qkv_g(
    const float* __restrict__ x, const float* __restrict__ w,
    uint64_t* __restrict__ qbits, uint64_t* __restrict__ kbits,
    int8_t* __restrict__ vq8, double* __restrict__ qpart,
    double* __restrict__ kpart, const int* __restrict__ flag) {
  __shared__ float wsm[256][34];     // stride 34: 8B-aligned rows, 2-way banks
  __shared__ double xsm[RQ][32];     // staged f64 (broadcast reads)

  const int f = flag[0];
  const int t = threadIdx.x;
  const int cBase = blockIdx.x * 256;
  const int c = cBase + t;              // 0..2303
  const int row0 = blockIdx.y * RQ;

  double acc[RQ];
  #pragma unroll
  for (int i = 0; i < RQ; i++) acc[i] = 0.0;

  if (f == 0) {
    for (int k0 = 0; k0 < CD; k0 += 32) {
      // stage w tile [256 c][32 k] via coalesced float4 (8 lines/wave-instr)
      #pragma unroll
      for (int j = 0; j < 8; j++) {
        const int flat = t + 256 * j;          // 0..2047
        const int r = flat >> 3, kq = flat & 7;
        const float4 v4 = *reinterpret_cast<const float4*>(
            w + (size_t)(cBase + r) * CD + k0 + kq * 4);
        wsm[r][kq * 4 + 0] = v4.x; wsm[r][kq * 4 + 1] = v4.y;
        wsm[r][kq * 4 + 2] = v4.z; wsm[r][kq * 4 + 3] = v4.w;
      }
      // stage x [16 rows][32 k] -> f64 (convert ONCE here)
      #pragma unroll
      for (int j = 0; j < 2; j++) {
        const int flat = t + 256 * j;          // 0..511
        const int r = flat >> 5, kk = flat & 31;
        xsm[r][kk] = (double)x[(size_t)(row0 + r) * CD + k0 + kk];
      }
      __syncthreads();
      // ascending kk per acc[i]: bit-identical accumulation order.
      // Preload all 16 double2 x-values -> 16 independent ds_read_b128
      // in flight, then the 32-FMA burst (needs the VGPR headroom from
      // __launch_bounds__(256,4)).
      for (int kk = 0; kk < 32; kk += 2) {
        double2 xv[RQ];
        #pragma unroll
        for (int i = 0; i < RQ; i++)
          xv[i] = *reinterpret_cast<const double2*>(&xsm[i][kk]);
        const float2 wf = *reinterpret_cast<const float2*>(&wsm[t][kk]);
        const double w0 = (double)wf.x;
        const double w1 = (double)wf.y;
        #pragma unroll
        for (int i = 0; i < RQ; i++) {
          acc[i] += xv[i].x * w0;
          acc[i] += xv[i].y * w1;
        }
      }
      __syncthreads();
    }
  } else {
    // F-order: consecutive out-channels contiguous -> already coalesced
    for (int k = 0; k < CD; k++) {
      const double wv = (double)w[(size_t)c + 2304u * (size_t)k];
      #pragma unroll
      for (int i = 0; i < RQ; i++) {
        const int row = row0 + i, b = row / NT, n = row - b * NT;
        acc[i] += (double)x[(size_t)b + 64u * (size_t)n + 12608u * (size_t)k] * wv;
      }
    }
  }

  // fused quantize epilogue (identical per-row math to R12/R14)
  const int kind = cBase / CD;              // uniform per block (768 % 256 == 0)
  const int h = (c - kind * CD) >> 6;       // uniform per wave
  const int lane = t & 63;                  // == dd
  #pragma unroll
  for (int i = 0; i < RQ; i++) {
    const int row = row0 + i, b = row / NT, n = row - b * NT;
    const int bh = b * HH + h;
    const double a = acc[i];
    if (kind == 2) {
      const double sV = 2.0 / 127.0;
      double vc = fmin(fmax(a, -2.0), 2.0);
      double vq = rint(vc / sV);
      vq = fmin(fmax(vq, -127.0), 127.0);
      vq8[(size_t)(bh * NT + n) * 64 + lane] = (int8_t)(int)vq;
    } else {
      const uint64_t msk = __ballot(a < 0.0);
      double s = fabs(a);
      #pragma unroll
      for (int off = 1; off < 64; off <<= 1) s += __shfl_xor(s, off);
      if (lane == 0) {
        if (kind == 0) { qbits[(size_t)bh * NT + n] = msk; qpart[(size_t)bh * NT + n] = s; }
        else           { kbits[(size_t)bh * NT + n] = msk; kpart[(size_t)bh * NT + n] = s; }
      }
    }
  }
}

// ---------- 1b) deterministic fixed-order reduction of row partials ----------
// grid (768), block 256. sqa[bh] = sum_n qpart[bh*197+n] in a FIXED tree order.
__global__ __launch_bounds__(256) void reduce_s(
    const double* __restrict__ qpart, const double* __restrict__ kpart,
    double* __restrict__ sqa, double* __restrict__ ska) {
  __shared__ double sh[256];
  const int bh = blockIdx.x, t = threadIdx.x;
  sh[t] = (t < NT) ? qpart[(size_t)bh * NT + t] : 0.0;
  __syncthreads();
  for (int s = 128; s > 0; s >>= 1) { if (t < s) sh[t] += sh[t + s]; __syncthreads(); }
  if (t == 0) sqa[bh] = sh[0];
  __syncthreads();
  sh[t] = (t < NT) ? kpart[(size_t)bh * NT + t] : 0.0;
  __syncthreads();
  for (int s = 128; s > 0; s >>= 1) { if (t < s) sh[t] += sh[t + s]; __syncthreads(); }
  if (t == 0) ska[bh] = sh[0];
}

// ---------- 2) attention in f64: one block per (b,h), loop n ----------
// grid (768), block 256. LDS-staged q/k bitrows + V(int16). Per-n math
// (trees, PV split, expressions) bit-identical to the R14 passing version.
__global__ __launch_bounds__(256) void attn_f64(
    const uint64_t* __restrict__ qbits, const uint64_t* __restrict__ kbits,
    const int8_t* __restrict__ vq8, const double* __restrict__ sqa,
    const double* __restrict__ ska, const float* __restrict__ rel_table,
    const int* __restrict__ rel_index, int* __restrict__ attn_acc,
    const int* __restrict__ flag) {
  __shared__ double ls[256];
  __shared__ double es[256];
  __shared__ int Pu[NT];
  __shared__ int part[4][64];
  __shared__ uint64_t qsh[NT];
  __shared__ uint64_t ksh[NT];
  __shared__ short vsh[NT * 64];   // 25.2 KB, int16 (2-way banks on PV reads)

  const int f = flag[0];
  const int bh = blockIdx.x;
  const int b = bh / HH, h = bh - b * HH;
  const int t = threadIdx.x;

  const double s_q = sqa[bh] / (double)(NT * 64);
  const double s_k = ska[bh] / (double)(NT * 64);
  const double coef = s_q * s_k * 0.125;

  if (t < NT) {
    qsh[t] = qbits[(size_t)bh * NT + t];
    ksh[t] = kbits[(size_t)bh * NT + t];
  }
  {
    const int* vsrc = (const int*)(vq8 + (size_t)bh * NT * 64);
    for (int idx = t; idx < NT * 16; idx += 256) {   // 3152 int32 words
      const int v4 = vsrc[idx];
      vsh[idx * 4 + 0] = (short)(signed char)(v4 & 0xff);
      vsh[idx * 4 + 1] = (short)(signed char)((v4 >> 8) & 0xff);
      vsh[idx * 4 + 2] = (short)(signed char)((v4 >> 16) & 0xff);
      vsh[idx * 4 + 3] = (short)(signed char)((v4 >> 24) & 0xff);
    }
  }
  __syncthreads();

  int* aout = attn_acc + (size_t)(b * NT) * CD + h * 64;   // + n*CD + dd

  for (int n = 0; n < NT; n++) {
    const uint64_t qb = qsh[n];
    double lt;
    if (t < NT) {
      const int dot = 64 - 2 * (int)__popcll(qb ^ ksh[t]);
      lt = coef * (double)dot +
           (double)rel_table[idxRT(f, rel_index[idxRI(f, n, t)], h)];
    } else {
      lt = -1e300;
    }
    ls[t] = lt;
    __syncthreads();
    for (int s = 128; s > 0; s >>= 1) {      // exact max (order-independent)
      if (t < s) ls[t] = fmax(ls[t], ls[t + s]);
      __syncthreads();
    }
    const double mx = ls[0];
    const double et = (t < NT) ? exp(lt - mx) : 0.0;
    es[t] = et;
    __syncthreads();
    for (int s = 128; s > 0; s >>= 1) {      // fixed-order sum (deterministic)
      if (t < s) es[t] += es[t + s];
      __syncthreads();
    }
    const double sum = es[0];

    if (t < NT) {
      const double sP = 1.0 / 255.0;
      double P = rint((et / sum) / sP);
      P = fmin(fmax(P, 0.0), 255.0);
      Pu[t] = (int)P;
    }
    __syncthreads();

    // PV: all 4 waves, same partial split as R14 (exactly deterministic).
    {
      const int wv = t >> 6, dd = t & 63;
      const int m0 = wv * 50, m1 = (wv == 3) ? NT : m0 + 50;
      int acc = 0;
      for (int m = m0; m < m1; m++) acc += Pu[m] * (int)vsh[m * 64 + dd];
      part[wv][dd] = acc;
    }
    __syncthreads();
    if (t < 64) {
      aout[(size_t)n * CD + t] = part[0][t] + part[1][t] + part[2][t] + part[3][t];
    }
    // no trailing barrier needed: next n's first write (ls) is its own slot,
    // and part/Pu are only rewritten after >=2 barriers in iteration n+1.
  }
}

// ---------- 3) proj GEMM, f64 accum, LDS-tiled, 16 rows/block ----------
// grid (3, 788), block 256. out = (sum acc_int*w)*sP*sV + bias, fp32.
__global__ __launch_bounds__(256, 4) void proj_g(
    const int* __restrict__ attn_acc, const float* __restrict__ w,
    const float* __restrict__ bias, float* __restrict__ out,
    const int* __restrict__ flag) {
  __shared__ float wsm[256][34];
  __shared__ double xsm[RQ][32];     // staged int->f64 (exact), broadcast reads

  const int f = flag[0];
  const int t = threadIdx.x;
  const int cBase = blockIdx.x * 256;
  const int c = cBase + t;                  // 0..767
  const int row0 = blockIdx.y * RQ;

  double acc[RQ];
  #pragma unroll
  for (int i = 0; i < RQ; i++) acc[i] = 0.0;

  if (f == 0) {
    for (int k0 = 0; k0 < CD; k0 += 32) {
      #pragma unroll
      for (int j = 0; j < 8; j++) {
        const int flat = t + 256 * j;
        const int r = flat >> 3, kq = flat & 7;
        const float4 v4 = *reinterpret_cast<const float4*>(
            w + (size_t)(cBase + r) * CD + k0 + kq * 4);
        wsm[r][kq * 4 + 0] = v4.x; wsm[r][kq * 4 + 1] = v4.y;
        wsm[r][kq * 4 + 2] = v4.z; wsm[r][kq * 4 + 3] = v4.w;
      }
      #pragma unroll
      for (int j = 0; j < 2; j++) {
        const int flat = t + 256 * j;          // 0..511
        const int r = flat >> 5, kk = flat & 31;
        xsm[r][kk] = (double)attn_acc[(size_t)(row0 + r) * CD + k0 + kk];
      }
      __syncthreads();
      for (int kk = 0; kk < 32; kk += 2) {
        double2 xv[RQ];
        #pragma unroll
        for (int i = 0; i < RQ; i++)
          xv[i] = *reinterpret_cast<const double2*>(&xsm[i][kk]);
        const float2 wf = *reinterpret_cast<const float2*>(&wsm[t][kk]);
        const double w0 = (double)wf.x;
        const double w1 = (double)wf.y;
        #pragma unroll
        for (int i = 0; i < RQ; i++) {
          acc[i] += xv[i].x * w0;
          acc[i] += xv[i].y * w1;
        }
      }
      __syncthreads();
    }
  } else {
    for (int k = 0; k < CD; k++) {
      const double wv = (double)w[(size_t)c + 768u * (size_t)k];
      #pragma unroll
      for (int i = 0; i < RQ; i++)
        acc[i] += (double)attn_acc[(size_t)(row0 + i) * CD + k] * wv;
    }
  }

  const double SCALE = (1.0 / 255.0) * (2.0 / 127.0);
  #pragma unroll
  for (int i = 0; i < RQ; i++) {
    const int row = row0 + i, b = row / NT, n = row - b * NT;
    out[idxX(f, b, n, c)] = (float)(acc[i] * SCALE + (double)bias[c]);
  }
}

// ---------------- host launch ----------------
extern "C" void kernel_launch(void* const* d_in, const int* in_sizes, int n_in,
                              void* d_out, int out_size, void* d_ws, size_t ws_size,
                              hipStream_t stream) {
  (void)out_size; (void)ws_size;

  // resolve inputs BY ELEMENT COUNT (all unique; fallback positional)
  const float* x = nullptr;
  const float* qkv_w = nullptr;
  const float* proj_w = nullptr;
  const float* proj_b = nullptr;
  const float* rel_table = nullptr;
  const int* rel_index = nullptr;
  for (int i = 0; i < n_in; i++) {
    switch (in_sizes[i]) {
      case 9682944: x         = (const float*)d_in[i]; break;
      case 1769472: qkv_w     = (const float*)d_in[i]; break;
      case 589824:  proj_w    = (const float*)d_in[i]; break;
      case 768:     proj_b    = (const float*)d_in[i]; break;
      case 8784:    rel_table = (const float*)d_in[i]; break;
      case 38809:   rel_index = (const int*)d_in[i];   break;
      default: break;
    }
  }
  if (!x)         x         = (const float*)d_in[0];
  if (!qkv_w)     qkv_w     = (const float*)d_in[1];
  if (!proj_w)    proj_w    = (const float*)d_in[2];
  if (!proj_b)    proj_b    = (const float*)d_in[3];
  if (!rel_table) rel_table = (const float*)d_in[4];
  if (!rel_index) rel_index = (const int*)d_in[5];
  float* out = (float*)d_out;

  uint8_t* ws = (uint8_t*)d_ws;
  // workspace (~53 MB), every byte written before read each call, no init:
  int*      flag     = (int*)(ws + 0);              //         64
  double*   sqa      = (double*)(ws + 64);          //      6,144
  double*   ska      = (double*)(ws + 6208);        //      6,144
  double*   qpart    = (double*)(ws + 12352);       //  1,210,368
  double*   kpart    = (double*)(ws + 1222720);     //  1,210,368
  uint64_t* qbits    = (uint64_t*)(ws + 2433088);   //  1,210,368
  uint64_t* kbits    = (uint64_t*)(ws + 3643456);   //  1,210,368
  int8_t*   vq8      = (int8_t*)(ws + 4853824);     //  9,682,944
  int*      attn_acc = (int*)(ws + 14536768);       // 38,731,776 -> 53,268,544

  probe_orient<<<1, 64, 0, stream>>>(rel_index, flag);
  qkv_g<<<dim3(9, YB), 256, 0, stream>>>(x, qkv_w, qbits, kbits, vq8,
                                         qpart, kpart, flag);
  reduce_s<<<NBH, 256, 0, stream>>>(qpart, kpart, sqa, ska);
  attn_f64<<<NBH, 256, 0, stream>>>(qbits, kbits, vq8, sqa, ska,
                                    rel_table, rel_index, attn_acc, flag);
  proj_g<<<dim3(3, YB), 256, 0, stream>>>(attn_acc, proj_w, proj_b, out, flag);
}

// Round 6
// 2062.204 us; speedup vs baseline: 1.7630x; 1.3720x over previous
//
#include <hip/hip_runtime.h>
#include <stdint.h>

// BinaryAttention on MI355X (gfx950).  B=64, N=197, C=768, H=12, d=64.
//
// ROUND 17 — resubmit of R16 (GPU acquisition timeout; no kernel signal).
// R16 theory: R15 qkv 1.68 ms, VALUBusy 44%; inner loop issued 17 LDS reads
// per 32 FMAs -> issue-mix bound, neither pipe saturated. This version
// changes the THREAD TILE only: each thread computes 4 cols (stride 64) x
// 8 rows => per kk-pair: 8 broadcast ds_read_b128 (x) + 4 ds_read_b64 (w)
// + 64 FMAs (0.19 LDS instr/FMA vs 0.53). Per-output accumulation order is
// BIT-IDENTICAL (ascending k, same two adds per kk-pair) -> absmax
// unchanged. Epilogue: lane==dd still holds (cols at stride 64), ballot
// logic unchanged. attn_f64 / reduce_s are the R15 passing versions.

#define NT 197
#define HH 12
#define CD 768
#define NB 64
#define MROWS (NB * NT)   // 12608
#define NBH (NB * HH)     // 768
#define RB 32             // rows per block
#define YB (MROWS / RB)   // 394

// ---- flag-selected flat indexers (flag: 0 = C-order, 1 = F-order) ----
__device__ __forceinline__ size_t idxX(int f, int b, int n, int c) {
  return f ? ((size_t)b + 64u * (size_t)n + 12608u * (size_t)c)
           : ((size_t)(b * NT + n) * CD + c);
}
__device__ __forceinline__ size_t idxRT(int f, int i, int h) {  // rel_table [732,12]
  return f ? ((size_t)i + 732u * (size_t)h) : ((size_t)i * HH + h);
}
__device__ __forceinline__ size_t idxRI(int f, int n, int m) {  // rel_index [197,197]
  return f ? ((size_t)n + 197u * (size_t)m) : ((size_t)n * NT + m);
}

// ---- orientation probe (deterministic rel_index: C: ri[1]=729, ri[197]=730) --
__global__ __launch_bounds__(64) void probe_orient(const int* __restrict__ ri,
                                                   int* __restrict__ flag) {
  if (threadIdx.x == 0) {
    const int a = ri[1], b = ri[197];
    flag[0] = (a == 730 && b == 729) ? 1 : 0;
  }
}

// ---------- 1) qkv GEMM, f64 accum, LDS-tiled, 4x8 register tile ----------
// grid (9, 394), block 256. Block tile: cols cBase..cBase+255, rows row0..+31.
// Thread (wv = t>>6, lane = t&63): cols cBase+lane+64j (j=0..3),
// rows row0+wv*8+i (i=0..7).
__global__ __launch_bounds__(256, 3) void qkv_g(
    const float* __restrict__ x, const float* __restrict__ w,
    uint64_t* __restrict__ qbits, uint64_t* __restrict__ kbits,
    int8_t* __restrict__ vq8, double* __restrict__ qpart,
    double* __restrict__ kpart, const int* __restrict__ flag) {
  __shared__ float wsm[256][34];     // 34.8 KB; stride 34: 8B-aligned rows
  __shared__ double xsm[RB][32];     // 8 KB staged f64 (broadcast reads)

  const int f = flag[0];
  const int t = threadIdx.x;
  const int wv = t >> 6, lane = t & 63;
  const int cBase = blockIdx.x * 256;
  const int row0 = blockIdx.y * RB;

  double acc[4][8];
  #pragma unroll
  for (int j = 0; j < 4; j++)
    #pragma unroll
    for (int i = 0; i < 8; i++) acc[j][i] = 0.0;

  if (f == 0) {
    for (int k0 = 0; k0 < CD; k0 += 32) {
      // stage w tile [256 c][32 k] via coalesced float4
      #pragma unroll
      for (int j = 0; j < 8; j++) {
        const int flat = t + 256 * j;          // 0..2047
        const int r = flat >> 3, kq = flat & 7;
        const float4 v4 = *reinterpret_cast<const float4*>(
            w + (size_t)(cBase + r) * CD + k0 + kq * 4);
        wsm[r][kq * 4 + 0] = v4.x; wsm[r][kq * 4 + 1] = v4.y;
        wsm[r][kq * 4 + 2] = v4.z; wsm[r][kq * 4 + 3] = v4.w;
      }
      // stage x [32 rows][32 k] -> f64 (convert ONCE here)
      #pragma unroll
      for (int j = 0; j < 4; j++) {
        const int flat = t + 256 * j;          // 0..1023
        const int r = flat >> 5, kk = flat & 31;
        xsm[r][kk] = (double)x[(size_t)(row0 + r) * CD + k0 + kk];
      }
      __syncthreads();
      // ascending kk, += x.x*w0 then += x.y*w1 per pair: bit-identical order
      for (int kk = 0; kk < 32; kk += 2) {
        double2 xv[8];
        #pragma unroll
        for (int i = 0; i < 8; i++)
          xv[i] = *reinterpret_cast<const double2*>(&xsm[wv * 8 + i][kk]);
        double w0[4], w1[4];
        #pragma unroll
        for (int j = 0; j < 4; j++) {
          const float2 wf = *reinterpret_cast<const float2*>(&wsm[lane + 64 * j][kk]);
          w0[j] = (double)wf.x; w1[j] = (double)wf.y;
        }
        #pragma unroll
        for (int j = 0; j < 4; j++)
          #pragma unroll
          for (int i = 0; i < 8; i++) {
            acc[j][i] += xv[i].x * w0[j];
            acc[j][i] += xv[i].y * w1[j];
          }
      }
      __syncthreads();
    }
  } else {
    // F-order fallback: direct global reads, same accumulation order
    for (int k = 0; k < CD; k++) {
      double w0[4];
      #pragma unroll
      for (int j = 0; j < 4; j++)
        w0[j] = (double)w[(size_t)(cBase + lane + 64 * j) + 2304u * (size_t)k];
      #pragma unroll
      for (int i = 0; i < 8; i++) {
        const int row = row0 + wv * 8 + i, b = row / NT, n = row - b * NT;
        const double xv = (double)x[(size_t)b + 64u * (size_t)n + 12608u * (size_t)k];
        #pragma unroll
        for (int j = 0; j < 4; j++) acc[j][i] += xv * w0[j];
      }
    }
  }

  // fused quantize epilogue (identical per-(row,head) math to R15)
  const int kind = cBase / CD;                  // uniform per block
  const int hBase = (cBase - kind * CD) >> 6;   // h = hBase + j
  #pragma unroll
  for (int j = 0; j < 4; j++) {
    const int h = hBase + j;
    #pragma unroll
    for (int i = 0; i < 8; i++) {
      const int row = row0 + wv * 8 + i, b = row / NT, n = row - b * NT;
      const int bh = b * HH + h;
      const double a = acc[j][i];
      if (kind == 2) {
        const double sV = 2.0 / 127.0;
        double vc = fmin(fmax(a, -2.0), 2.0);
        double vq = rint(vc / sV);
        vq = fmin(fmax(vq, -127.0), 127.0);
        vq8[(size_t)(bh * NT + n) * 64 + lane] = (int8_t)(int)vq;
      } else {
        const uint64_t msk = __ballot(a < 0.0);
        double s = fabs(a);
        #pragma unroll
        for (int off = 1; off < 64; off <<= 1) s += __shfl_xor(s, off);
        if (lane == 0) {
          if (kind == 0) { qbits[(size_t)bh * NT + n] = msk; qpart[(size_t)bh * NT + n] = s; }
          else           { kbits[(size_t)bh * NT + n] = msk; kpart[(size_t)bh * NT + n] = s; }
        }
      }
    }
  }
}

// ---------- 1b) deterministic fixed-order reduction of row partials ----------
__global__ __launch_bounds__(256) void reduce_s(
    const double* __restrict__ qpart, const double* __restrict__ kpart,
    double* __restrict__ sqa, double* __restrict__ ska) {
  __shared__ double sh[256];
  const int bh = blockIdx.x, t = threadIdx.x;
  sh[t] = (t < NT) ? qpart[(size_t)bh * NT + t] : 0.0;
  __syncthreads();
  for (int s = 128; s > 0; s >>= 1) { if (t < s) sh[t] += sh[t + s]; __syncthreads(); }
  if (t == 0) sqa[bh] = sh[0];
  __syncthreads();
  sh[t] = (t < NT) ? kpart[(size_t)bh * NT + t] : 0.0;
  __syncthreads();
  for (int s = 128; s > 0; s >>= 1) { if (t < s) sh[t] += sh[t + s]; __syncthreads(); }
  if (t == 0) ska[bh] = sh[0];
}

// ---------- 2) attention in f64: one block per (b,h), loop n (R15) ----------
__global__ __launch_bounds__(256) void attn_f64(
    const uint64_t* __restrict__ qbits, const uint64_t* __restrict__ kbits,
    const int8_t* __restrict__ vq8, const double* __restrict__ sqa,
    const double* __restrict__ ska, const float* __restrict__ rel_table,
    const int* __restrict__ rel_index, int* __restrict__ attn_acc,
    const int* __restrict__ flag) {
  __shared__ double ls[256];
  __shared__ double es[256];
  __shared__ int Pu[NT];
  __shared__ int part[4][64];
  __shared__ uint64_t qsh[NT];
  __shared__ uint64_t ksh[NT];
  __shared__ short vsh[NT * 64];   // 25.2 KB int16

  const int f = flag[0];
  const int bh = blockIdx.x;
  const int b = bh / HH, h = bh - b * HH;
  const int t = threadIdx.x;

  const double s_q = sqa[bh] / (double)(NT * 64);
  const double s_k = ska[bh] / (double)(NT * 64);
  const double coef = s_q * s_k * 0.125;

  if (t < NT) {
    qsh[t] = qbits[(size_t)bh * NT + t];
    ksh[t] = kbits[(size_t)bh * NT + t];
  }
  {
    const int* vsrc = (const int*)(vq8 + (size_t)bh * NT * 64);
    for (int idx = t; idx < NT * 16; idx += 256) {   // 3152 int32 words
      const int v4 = vsrc[idx];
      vsh[idx * 4 + 0] = (short)(signed char)(v4 & 0xff);
      vsh[idx * 4 + 1] = (short)(signed char)((v4 >> 8) & 0xff);
      vsh[idx * 4 + 2] = (short)(signed char)((v4 >> 16) & 0xff);
      vsh[idx * 4 + 3] = (short)(signed char)((v4 >> 24) & 0xff);
    }
  }
  __syncthreads();

  int* aout = attn_acc + (size_t)(b * NT) * CD + h * 64;   // + n*CD + dd

  for (int n = 0; n < NT; n++) {
    const uint64_t qb = qsh[n];
    double lt;
    if (t < NT) {
      const int dot = 64 - 2 * (int)__popcll(qb ^ ksh[t]);
      lt = coef * (double)dot +
           (double)rel_table[idxRT(f, rel_index[idxRI(f, n, t)], h)];
    } else {
      lt = -1e300;
    }
    ls[t] = lt;
    __syncthreads();
    for (int s = 128; s > 0; s >>= 1) {      // exact max (order-independent)
      if (t < s) ls[t] = fmax(ls[t], ls[t + s]);
      __syncthreads();
    }
    const double mx = ls[0];
    const double et = (t < NT) ? exp(lt - mx) : 0.0;
    es[t] = et;
    __syncthreads();
    for (int s = 128; s > 0; s >>= 1) {      // fixed-order sum (deterministic)
      if (t < s) es[t] += es[t + s];
      __syncthreads();
    }
    const double sum = es[0];

    if (t < NT) {
      const double sP = 1.0 / 255.0;
      double P = rint((et / sum) / sP);
      P = fmin(fmax(P, 0.0), 255.0);
      Pu[t] = (int)P;
    }
    __syncthreads();

    // PV: all 4 waves, fixed partial split (exactly deterministic).
    {
      const int wv = t >> 6, dd = t & 63;
      const int m0 = wv * 50, m1 = (wv == 3) ? NT : m0 + 50;
      int acc = 0;
      for (int m = m0; m < m1; m++) acc += Pu[m] * (int)vsh[m * 64 + dd];
      part[wv][dd] = acc;
    }
    __syncthreads();
    if (t < 64) {
      aout[(size_t)n * CD + t] = part[0][t] + part[1][t] + part[2][t] + part[3][t];
    }
  }
}

// ---------- 3) proj GEMM, f64 accum, LDS-tiled, 4x8 register tile ----------
// grid (3, 394), block 256.
__global__ __launch_bounds__(256, 3) void proj_g(
    const int* __restrict__ attn_acc, const float* __restrict__ w,
    const float* __restrict__ bias, float* __restrict__ out,
    const int* __restrict__ flag) {
  __shared__ float wsm[256][34];
  __shared__ double xsm[RB][32];     // staged int->f64 (exact)

  const int f = flag[0];
  const int t = threadIdx.x;
  const int wv = t >> 6, lane = t & 63;
  const int cBase = blockIdx.x * 256;
  const int row0 = blockIdx.y * RB;

  double acc[4][8];
  #pragma unroll
  for (int j = 0; j < 4; j++)
    #pragma unroll
    for (int i = 0; i < 8; i++) acc[j][i] = 0.0;

  if (f == 0) {
    for (int k0 = 0; k0 < CD; k0 += 32) {
      #pragma unroll
      for (int j = 0; j < 8; j++) {
        const int flat = t + 256 * j;
        const int r = flat >> 3, kq = flat & 7;
        const float4 v4 = *reinterpret_cast<const float4*>(
            w + (size_t)(cBase + r) * CD + k0 + kq * 4);
        wsm[r][kq * 4 + 0] = v4.x; wsm[r][kq * 4 + 1] = v4.y;
        wsm[r][kq * 4 + 2] = v4.z; wsm[r][kq * 4 + 3] = v4.w;
      }
      #pragma unroll
      for (int j = 0; j < 4; j++) {
        const int flat = t + 256 * j;          // 0..1023
        const int r = flat >> 5, kk = flat & 31;
        xsm[r][kk] = (double)attn_acc[(size_t)(row0 + r) * CD + k0 + kk];
      }
      __syncthreads();
      for (int kk = 0; kk < 32; kk += 2) {
        double2 xv[8];
        #pragma unroll
        for (int i = 0; i < 8; i++)
          xv[i] = *reinterpret_cast<const double2*>(&xsm[wv * 8 + i][kk]);
        double w0[4], w1[4];
        #pragma unroll
        for (int j = 0; j < 4; j++) {
          const float2 wf = *reinterpret_cast<const float2*>(&wsm[lane + 64 * j][kk]);
          w0[j] = (double)wf.x; w1[j] = (double)wf.y;
        }
        #pragma unroll
        for (int j = 0; j < 4; j++)
          #pragma unroll
          for (int i = 0; i < 8; i++) {
            acc[j][i] += xv[i].x * w0[j];
            acc[j][i] += xv[i].y * w1[j];
          }
      }
      __syncthreads();
    }
  } else {
    for (int k = 0; k < CD; k++) {
      double w0[4];
      #pragma unroll
      for (int j = 0; j < 4; j++)
        w0[j] = (double)w[(size_t)(cBase + lane + 64 * j) + 768u * (size_t)k];
      #pragma unroll
      for (int i = 0; i < 8; i++) {
        const double xv = (double)attn_acc[(size_t)(row0 + wv * 8 + i) * CD + k];
        #pragma unroll
        for (int j = 0; j < 4; j++) acc[j][i] += xv * w0[j];
      }
    }
  }

  const double SCALE = (1.0 / 255.0) * (2.0 / 127.0);
  #pragma unroll
  for (int j = 0; j < 4; j++) {
    const int c = cBase + lane + 64 * j;
    const double bj = (double)bias[c];
    #pragma unroll
    for (int i = 0; i < 8; i++) {
      const int row = row0 + wv * 8 + i, b = row / NT, n = row - b * NT;
      out[idxX(f, b, n, c)] = (float)(acc[j][i] * SCALE + bj);
    }
  }
}

// ---------------- host launch ----------------
extern "C" void kernel_launch(void* const* d_in, const int* in_sizes, int n_in,
                              void* d_out, int out_size, void* d_ws, size_t ws_size,
                              hipStream_t stream) {
  (void)out_size; (void)ws_size;

  // resolve inputs BY ELEMENT COUNT (all unique; fallback positional)
  const float* x = nullptr;
  const float* qkv_w = nullptr;
  const float* proj_w = nullptr;
  const float* proj_b = nullptr;
  const float* rel_table = nullptr;
  const int* rel_index = nullptr;
  for (int i = 0; i < n_in; i++) {
    switch (in_sizes[i]) {
      case 9682944: x         = (const float*)d_in[i]; break;
      case 1769472: qkv_w     = (const float*)d_in[i]; break;
      case 589824:  proj_w    = (const float*)d_in[i]; break;
      case 768:     proj_b    = (const float*)d_in[i]; break;
      case 8784:    rel_table = (const float*)d_in[i]; break;
      case 38809:   rel_index = (const int*)d_in[i];   break;
      default: break;
    }
  }
  if (!x)         x         = (const float*)d_in[0];
  if (!qkv_w)     qkv_w     = (const float*)d_in[1];
  if (!proj_w)    proj_w    = (const float*)d_in[2];
  if (!proj_b)    proj_b    = (const float*)d_in[3];
  if (!rel_table) rel_table = (const float*)d_in[4];
  if (!rel_index) rel_index = (const int*)d_in[5];
  float* out = (float*)d_out;

  uint8_t* ws = (uint8_t*)d_ws;
  // workspace (~53 MB), every byte written before read each call, no init:
  int*      flag     = (int*)(ws + 0);              //         64
  double*   sqa      = (double*)(ws + 64);          //      6,144
  double*   ska      = (double*)(ws + 6208);        //      6,144
  double*   qpart    = (double*)(ws + 12352);       //  1,210,368
  double*   kpart    = (double*)(ws + 1222720);     //  1,210,368
  uint64_t* qbits    = (uint64_t*)(ws + 2433088);   //  1,210,368
  uint64_t* kbits    = (uint64_t*)(ws + 3643456);   //  1,210,368
  int8_t*   vq8      = (int8_t*)(ws + 4853824);     //  9,682,944
  int*      attn_acc = (int*)(ws + 14536768);       // 38,731,776 -> 53,268,544

  probe_orient<<<1, 64, 0, stream>>>(rel_index, flag);
  qkv_g<<<dim3(9, YB), 256, 0, stream>>>(x, qkv_w, qbits, kbits, vq8,
                                         qpart, kpart, flag);
  reduce_s<<<NBH, 256, 0, stream>>>(qpart, kpart, sqa, ska);
  attn_f64<<<NBH, 256, 0, stream>>>(qbits, kbits, vq8, sqa, ska,
                                    rel_table, rel_index, attn_acc, flag);
  proj_g<<<dim3(3, YB), 256, 0, stream>>>(attn_acc, proj_w, proj_b, out, flag);
}